// Round 9
// baseline (640.046 us; speedup 1.0000x reference)
//
#include <hip/hip_runtime.h>

typedef short short8 __attribute__((ext_vector_type(8)));
typedef short short4_t __attribute__((ext_vector_type(4)));
typedef float floatx4 __attribute__((ext_vector_type(4)));
typedef unsigned short ushort_t;

#define B_ 16
#define S_ 128
#define T_ 64
#define H_ 128
#define FF_ 256
#define SCALEQK 0.25f

// bf16 transposed-weight pool offsets (ushort units)
#define OFFP 0
#define OFFQ(l) (16384 + (l) * 65536)
#define OFFK(l) (OFFQ(l) + 16384)
#define OFFV(l) (OFFQ(l) + 32768)
#define OFFO(l) (OFFQ(l) + 49152)
#define OFFW1(l) (278528 + (l) * 65536)
#define OFFW2(l) (OFFW1(l) + 32768)

__device__ __forceinline__ float b2f(ushort_t u) {
    union { unsigned int i; float f; } x; x.i = ((unsigned int)u) << 16; return x.f;
}
__device__ __forceinline__ ushort_t f2b(float f) {
    union { float f; unsigned int i; } x; x.f = f;
    unsigned int r = x.i + 0x7fffu + ((x.i >> 16) & 1u);
    return (ushort_t)(r >> 16);
}
__device__ __forceinline__ int pack2b(float a, float b) {
    return (int)f2b(a) | ((int)f2b(b) << 16);
}

// ---------------------------------------------------------------------------
// Weight preconvert: fp32 W[K][N] -> bf16 wT[N][K] (round-2 proven).
// ---------------------------------------------------------------------------
struct WtEnt { const float* src; int N; int K; int nclog2; int dstoff; };
struct WtArgs { WtEnt e[25]; };

__global__ __launch_bounds__(256) void wt_kernel(WtArgs a, ushort_t* __restrict__ dst) {
    WtEnt ent = a.e[blockIdx.x];
    const int tiles_c = ent.N >> 5;
    const int nt = (ent.K >> 5) * tiles_c;
    const int t = blockIdx.y;
    if (t >= nt) return;
    const int tc = t & (tiles_c - 1);
    const int tr = t >> ent.nclog2;
    __shared__ float ld[32 * 33];
    const int tid = threadIdx.x;
#pragma unroll
    for (int i = 0; i < 4; ++i) {
        int e = tid + i * 256;
        int rr = e >> 5, cc = e & 31;
        ld[rr * 33 + cc] = ent.src[(tr * 32 + rr) * ent.N + tc * 32 + cc];
    }
    __syncthreads();
    ushort_t* d = dst + ent.dstoff;
#pragma unroll
    for (int i = 0; i < 4; ++i) {
        int e = tid + i * 256;
        int rr = e >> 5, cc = e & 31;
        d[(tc * 32 + rr) * ent.K + tr * 32 + cc] = f2b(ld[cc * 33 + rr]);
    }
}

// ---------------------------------------------------------------------------
// Round-5 proven helpers (original orientation).
// ---------------------------------------------------------------------------
template<int RT, int CT, int KK>
__device__ __forceinline__ void mm_g(const ushort_t* aL, int sa,
                                     const ushort_t* __restrict__ wT,
                                     int colbase, int lane, floatx4 (&acc)[RT][CT]) {
    const int l15 = lane & 15, lq8 = (lane >> 4) * 8;
#pragma unroll
    for (int r = 0; r < RT; ++r)
#pragma unroll
        for (int c = 0; c < CT; ++c) acc[r][c] = (floatx4){0.f, 0.f, 0.f, 0.f};
#pragma unroll
    for (int k0 = 0; k0 < KK; k0 += 32) {
        short8 b[CT];
#pragma unroll
        for (int c = 0; c < CT; ++c)
            b[c] = *(const short8*)&wT[(colbase + c * 16 + l15) * KK + k0 + lq8];
#pragma unroll
        for (int r = 0; r < RT; ++r) {
            short8 a = *(const short8*)&aL[(r * 16 + l15) * sa + k0 + lq8];
#pragma unroll
            for (int c = 0; c < CT; ++c)
                acc[r][c] = __builtin_amdgcn_mfma_f32_16x16x32_bf16(a, b[c], acc[r][c], 0, 0, 0);
        }
    }
}

template<int RT, int CT>
__device__ __forceinline__ void add_bias(floatx4 (&acc)[RT][CT], const float* b,
                                         int colbase, int l15) {
#pragma unroll
    for (int c = 0; c < CT; ++c) {
        float bc = b[colbase + c * 16 + l15];
#pragma unroll
        for (int r = 0; r < RT; ++r)
#pragma unroll
            for (int g = 0; g < 4; ++g) acc[r][c][g] += bc;
    }
}

template<int RT, int CT>
__device__ __forceinline__ void add_resid_reg(floatx4 (&acc)[RT][CT],
                                              const float (&res)[RT][CT][4]) {
#pragma unroll
    for (int r = 0; r < RT; ++r)
#pragma unroll
        for (int c = 0; c < CT; ++c)
#pragma unroll
            for (int g = 0; g < 4; ++g) acc[r][c][g] += res[r][c][g];
}
template<int RT, int CT>
__device__ __forceinline__ void save_resid(float (&res)[RT][CT][4],
                                           const floatx4 (&acc)[RT][CT]) {
#pragma unroll
    for (int r = 0; r < RT; ++r)
#pragma unroll
        for (int c = 0; c < CT; ++c)
#pragma unroll
            for (int g = 0; g < 4; ++g) res[r][c][g] = acc[r][c][g];
}

template<int RT, int CT>
__device__ __forceinline__ void st_n(const floatx4 (&acc)[RT][CT], ushort_t* dst, int stride,
                                     int colbase, int l15, int lq) {
#pragma unroll
    for (int r = 0; r < RT; ++r)
#pragma unroll
        for (int g = 0; g < 4; ++g) {
            int row = r * 16 + lq * 4 + g;
#pragma unroll
            for (int c = 0; c < CT; ++c)
                dst[row * stride + colbase + c * 16 + l15] = f2b(acc[r][c][g]);
        }
}

template<int RT, int CT>
__device__ __forceinline__ void st_t(const floatx4 (&acc)[RT][CT], ushort_t* dst, int stride,
                                     int colbase, int l15, int lq) {
#pragma unroll
    for (int r = 0; r < RT; ++r)
#pragma unroll
        for (int c = 0; c < CT; ++c) {
            int d = colbase + c * 16 + l15;
            short4_t p;
#pragma unroll
            for (int g = 0; g < 4; ++g) p[g] = (short)f2b(acc[r][c][g]);
            *(short4_t*)&dst[d * stride + r * 16 + lq * 4] = p;
        }
}

// LayerNorm, original layout, NW participating waves (stride 2*NW in redL).
// NW=4 is byte-identical to the round-5 ln_norm.
template<int RT, int CT, int NW>
__device__ __forceinline__ void ln_norm(floatx4 (&acc)[RT][CT], float* redL,
                                        const float* lns, const float* lnb,
                                        int colbase, int l15, int lq, int wv) {
#pragma unroll
    for (int r = 0; r < RT; ++r)
#pragma unroll
        for (int g = 0; g < 4; ++g) {
            float s = 0.f, q = 0.f;
#pragma unroll
            for (int c = 0; c < CT; ++c) { float v = acc[r][c][g]; s += v; q += v * v; }
            s += __shfl_xor(s, 1); s += __shfl_xor(s, 2); s += __shfl_xor(s, 4); s += __shfl_xor(s, 8);
            q += __shfl_xor(q, 1); q += __shfl_xor(q, 2); q += __shfl_xor(q, 4); q += __shfl_xor(q, 8);
            if (l15 == 0) {
                int row = r * 16 + lq * 4 + g;
                redL[row * 2 * NW + wv] = s;
                redL[row * 2 * NW + NW + wv] = q;
            }
        }
    __syncthreads();
#pragma unroll
    for (int r = 0; r < RT; ++r)
#pragma unroll
        for (int g = 0; g < 4; ++g) {
            int row = r * 16 + lq * 4 + g;
            float s = 0.f, q = 0.f;
#pragma unroll
            for (int w8 = 0; w8 < NW; w8 += 4) {
                float4 S = *(float4*)&redL[row * 2 * NW + w8];
                float4 Q = *(float4*)&redL[row * 2 * NW + NW + w8];
                s += S.x + S.y + S.z + S.w;
                q += Q.x + Q.y + Q.z + Q.w;
            }
            float mean = s * (1.f / 128.f);
            float var = q * (1.f / 128.f) - mean * mean;
            float rstd = rsqrtf(var + 1e-5f);
#pragma unroll
            for (int c = 0; c < CT; ++c) {
                int col = colbase + c * 16 + l15;
                acc[r][c][g] = (acc[r][c][g] - mean) * rstd * lns[col] + lnb[col];
            }
        }
}

template<int JT>
__device__ __forceinline__ void softmax_pack(floatx4 (&st)[JT], bool iv, unsigned jm,
                                             int (&px)[JT][2]) {
    float ev[JT][4];
    float mx = -3.0e38f;
#pragma unroll
    for (int jt = 0; jt < JT; ++jt)
#pragma unroll
        for (int g = 0; g < 4; ++g) {
            bool ok = iv && ((jm >> (jt * 4 + g)) & 1u);
            float s = ok ? st[jt][g] * SCALEQK : -1e9f;
            ev[jt][g] = s; mx = fmaxf(mx, s);
        }
    mx = fmaxf(mx, __shfl_xor(mx, 16)); mx = fmaxf(mx, __shfl_xor(mx, 32));
    float sum = 0.f;
#pragma unroll
    for (int jt = 0; jt < JT; ++jt)
#pragma unroll
        for (int g = 0; g < 4; ++g) { float e = __expf(ev[jt][g] - mx); ev[jt][g] = e; sum += e; }
    sum += __shfl_xor(sum, 16); sum += __shfl_xor(sum, 32);
    float inv = 1.f / sum;
#pragma unroll
    for (int jt = 0; jt < JT; ++jt) {
        px[jt][0] = pack2b(ev[jt][0] * inv, ev[jt][1] * inv);
        px[jt][1] = pack2b(ev[jt][2] * inv, ev[jt][3] * inv);
    }
}

__device__ __forceinline__ short8 pfrag(const int (*px)[2], int jc, int lq, int l15) {
    const int jA = (lq & 1) * 32 + l15;
    int a0 = __shfl(px[jc * 2][0], jA);
    int a1 = __shfl(px[jc * 2][1], jA);
    int a2 = __shfl(px[jc * 2][0], jA + 16);
    int a3 = __shfl(px[jc * 2][1], jA + 16);
    int b0 = __shfl(px[jc * 2 + 1][0], jA);
    int b1 = __shfl(px[jc * 2 + 1][1], jA);
    int b2 = __shfl(px[jc * 2 + 1][0], jA + 16);
    int b3 = __shfl(px[jc * 2 + 1][1], jA + 16);
    const bool t = (lq >> 1) != 0;
    union { int4 i; short8 s; } u;
    u.i = make_int4(t ? b0 : a0, t ? b1 : a1, t ? b2 : a2, t ? b3 : a3);
    return u.s;
}
__device__ __forceinline__ short8 vfrag(const ushort_t* vT, int stride, int row, int off) {
    int2 a = *(const int2*)&vT[row * stride + off];
    int2 b = *(const int2*)&vT[row * stride + off + 4];
    union { int4 i; short8 s; } u;
    u.i = make_int4(a.x, a.y, b.x, b.y);
    return u.s;
}

// ---------------------------------------------------------------------------
// K1 (round-5 proven, verbatim): per group gid (64 rows): input proj -> L0
// full -> L1 (kv + q@t0 + attn). Writes o1[gid][128] bf16 + xr0f[gid][128]
// fp32. 2048 blocks x 256 thr.
// ---------------------------------------------------------------------------
__global__ __launch_bounds__(256, 2) void k1_mega(
    const float* __restrict__ poly, const int* __restrict__ lens,
    const ushort_t* __restrict__ wt,
    const float* __restrict__ projb, const float* __restrict__ pls,
    const float* __restrict__ plb, const float* __restrict__ pos,
    const float* __restrict__ bq0, const float* __restrict__ bk0,
    const float* __restrict__ bv0, const float* __restrict__ bo0,
    const float* __restrict__ l1s0, const float* __restrict__ l1b0,
    const float* __restrict__ b10, const float* __restrict__ b20,
    const float* __restrict__ l2s0, const float* __restrict__ l2b0,
    const float* __restrict__ bq1, const float* __restrict__ bk1,
    const float* __restrict__ bv1,
    ushort_t* __restrict__ o1, float* __restrict__ xr0f)
{
    __shared__ ushort_t pool[34816];
    __shared__ float redL[512];
    __shared__ float psL[8 * 68];
    __shared__ float q1L[128];
    ushort_t* xL = pool;            // [64][136]
    ushort_t* qL = pool + 8704;     // [64][136]  (o written in-place per head)
    ushort_t* kL = pool + 17408;    // [64][136]
    ushort_t* vT = pool + 26112;    // [128][68]  v transposed
    ushort_t* hL = pool + 17408;    // [64][272]  FFN hidden, overlays kL+vT

    const int tid = threadIdx.x, lane = tid & 63, wv = tid >> 6;
    const int l15 = lane & 15, lq = lane >> 4;
    const int gid = blockIdx.x;
    const int len = lens[gid];

    // ---- stage poly -> xL (bf16, -1 pad) ----
    {
        const float* pg = poly + (size_t)gid * 8192;
#pragma unroll
        for (int it = 0; it < 8; ++it) {
            int e4 = (tid + it * 256) * 4;
            int row = e4 >> 7, col = e4 & 127;
            float4 f = *(const float4*)(pg + e4);
            if (row >= len) { f.x = -1.f; f.y = -1.f; f.z = -1.f; f.w = -1.f; }
            short4_t u;
            u[0] = (short)f2b(f.x); u[1] = (short)f2b(f.y);
            u[2] = (short)f2b(f.z); u[3] = (short)f2b(f.w);
            *(short4_t*)&xL[row * 136 + col] = u;
        }
    }
    __syncthreads();

    floatx4 a2[4][2];
    float xre[4][2][4];             // fp32 residual stream (this thread's slice)

    // ---- P1: input proj + LN + relu + pos -> xre, xL ----
    mm_g<4, 2, 128>(xL, 136, wt + OFFP, wv * 32, lane, a2);
    add_bias<4, 2>(a2, projb, wv * 32, l15);
    ln_norm<4, 2, 4>(a2, redL, pls, plb, wv * 32, l15, lq, wv);
    __syncthreads();               // done reading xL (staged poly) before overwrite
#pragma unroll
    for (int r = 0; r < 4; ++r)
#pragma unroll
        for (int gg = 0; gg < 4; ++gg) {
            int row = r * 16 + lq * 4 + gg;
#pragma unroll
            for (int c = 0; c < 2; ++c) {
                int col = wv * 32 + c * 16 + l15;
                float v = fmaxf(a2[r][c][gg], 0.f) + pos[row * 128 + col];
                xre[r][c][gg] = v;
                xL[row * 136 + col] = f2b(v);
            }
        }
    __syncthreads();

    // ---- P2: L0 QKV ----
    mm_g<4, 2, 128>(xL, 136, wt + OFFQ(0), wv * 32, lane, a2);
    add_bias<4, 2>(a2, bq0, wv * 32, l15);
    st_n<4, 2>(a2, qL, 136, wv * 32, l15, lq);
    mm_g<4, 2, 128>(xL, 136, wt + OFFK(0), wv * 32, lane, a2);
    add_bias<4, 2>(a2, bk0, wv * 32, l15);
    st_n<4, 2>(a2, kL, 136, wv * 32, l15, lq);
    mm_g<4, 2, 128>(xL, 136, wt + OFFV(0), wv * 32, lane, a2);
    add_bias<4, 2>(a2, bv0, wv * 32, l15);
    st_t<4, 2>(a2, vT, 68, wv * 32, l15, lq);
    __syncthreads();

    // ---- P3: L0 attention (MFMA S^T, reg softmax, shuffle-PV) ----
    {
        const int iRow = wv * 16 + l15;
        const bool iv = iRow < len;
        unsigned jm = 0;
#pragma unroll
        for (int jt = 0; jt < 4; ++jt)
#pragma unroll
            for (int gg = 0; gg < 4; ++gg)
                if (jt * 16 + lq * 4 + gg < len) jm |= (1u << (jt * 4 + gg));
        for (int h = 0; h < 8; ++h) {
            const int hc = h * 16;
            short8 z8 = {0, 0, 0, 0, 0, 0, 0, 0};
            short8 bqf = z8;
            if (lq < 2) bqf = *(const short8*)&qL[iRow * 136 + hc + lq * 8];
            floatx4 st[4];
#pragma unroll
            for (int jt = 0; jt < 4; ++jt) {
                short8 ak = z8;
                if (lq < 2) ak = *(const short8*)&kL[(jt * 16 + l15) * 136 + hc + lq * 8];
                floatx4 zz = {0.f, 0.f, 0.f, 0.f};
                st[jt] = __builtin_amdgcn_mfma_f32_16x16x32_bf16(ak, bqf, zz, 0, 0, 0);
            }
            int px[4][2];
            softmax_pack<4>(st, iv, jm, px);
            floatx4 ao = {0.f, 0.f, 0.f, 0.f};
#pragma unroll
            for (int jc = 0; jc < 2; ++jc) {
                short8 av = vfrag(vT, 68, hc + l15, jc * 32 + lq * 8);
                short8 bp = pfrag(px, jc, lq, l15);
                ao = __builtin_amdgcn_mfma_f32_16x16x32_bf16(av, bp, ao, 0, 0, 0);
            }
            short4_t w;
#pragma unroll
            for (int gg = 0; gg < 4; ++gg) w[gg] = (short)f2b(ao[gg]);
            *(short4_t*)&qL[iRow * 136 + hc + lq * 4] = w;
        }
    }
    __syncthreads();

    // ---- P4: O-proj + resid + LN -> xre, xL ----
    mm_g<4, 2, 128>(qL, 136, wt + OFFO(0), wv * 32, lane, a2);
    add_bias<4, 2>(a2, bo0, wv * 32, l15);
    add_resid_reg<4, 2>(a2, xre);
    ln_norm<4, 2, 4>(a2, redL, l1s0, l1b0, wv * 32, l15, lq, wv);
    save_resid<4, 2>(xre, a2);
    st_n<4, 2>(a2, xL, 136, wv * 32, l15, lq);
    __syncthreads();

    // ---- P5: FFN W1 + relu -> hL ----
    {
        floatx4 a4[4][4];
        mm_g<4, 4, 128>(xL, 136, wt + OFFW1(0), wv * 64, lane, a4);
        add_bias<4, 4>(a4, b10, wv * 64, l15);
#pragma unroll
        for (int r = 0; r < 4; ++r)
#pragma unroll
            for (int c = 0; c < 4; ++c)
#pragma unroll
                for (int gg = 0; gg < 4; ++gg) a4[r][c][gg] = fmaxf(a4[r][c][gg], 0.f);
        st_n<4, 4>(a4, hL, 272, wv * 64, l15, lq);
    }
    __syncthreads();

    // ---- P6: FFN W2 + resid + LN -> xre, xL; row0 -> xr0f (fp32) ----
    mm_g<4, 2, 256>(hL, 272, wt + OFFW2(0), wv * 32, lane, a2);
    add_bias<4, 2>(a2, b20, wv * 32, l15);
    add_resid_reg<4, 2>(a2, xre);
    ln_norm<4, 2, 4>(a2, redL, l2s0, l2b0, wv * 32, l15, lq, wv);
    save_resid<4, 2>(xre, a2);
    st_n<4, 2>(a2, xL, 136, wv * 32, l15, lq);
    if (lq == 0) {
#pragma unroll
        for (int c = 0; c < 2; ++c)
            xr0f[(size_t)gid * 128 + wv * 32 + c * 16 + l15] = a2[0][c][0];   // row 0
    }
    __syncthreads();

    // ---- P7: L1 K,V (full) + q at t=0 ----
    mm_g<4, 2, 128>(xL, 136, wt + OFFK(1), wv * 32, lane, a2);
    add_bias<4, 2>(a2, bk1, wv * 32, l15);
    st_n<4, 2>(a2, kL, 136, wv * 32, l15, lq);
    mm_g<4, 2, 128>(xL, 136, wt + OFFV(1), wv * 32, lane, a2);
    add_bias<4, 2>(a2, bv1, wv * 32, l15);
    st_t<4, 2>(a2, vT, 68, wv * 32, l15, lq);
    if (tid < 128) {
        int d = tid;
        float a = bq1[d];
        const ushort_t* wq = wt + OFFQ(1) + d * 128;
#pragma unroll 4
        for (int j0 = 0; j0 < 128; j0 += 8) {
            short8 w8 = *(const short8*)&wq[j0];
            short8 x8 = *(const short8*)&xL[j0];
#pragma unroll
            for (int q = 0; q < 8; ++q)
                a = fmaf(b2f((ushort_t)x8[q]), b2f((ushort_t)w8[q]), a);
        }
        q1L[d] = a;
    }
    __syncthreads();

    // ---- P8: L1 single-query attention -> o1 ----
    {
        int h = tid >> 5, jj = tid & 31;
        int hc = h * 16;
        float s[2];
#pragma unroll
        for (int half = 0; half < 2; ++half) {
            int j = jj + half * 32;
            float a = 0.f;
            short8 k0v = *(const short8*)&kL[j * 136 + hc];
            short8 k1v = *(const short8*)&kL[j * 136 + hc + 8];
#pragma unroll
            for (int q = 0; q < 8; ++q) {
                a = fmaf(q1L[hc + q], b2f((ushort_t)k0v[q]), a);
                a = fmaf(q1L[hc + 8 + q], b2f((ushort_t)k1v[q]), a);
            }
            s[half] = (j < len) ? a * SCALEQK : -1e9f;
        }
        float mx = fmaxf(s[0], s[1]);
#pragma unroll
        for (int d = 1; d < 32; d <<= 1) mx = fmaxf(mx, __shfl_xor(mx, d));
        float e0 = __expf(s[0] - mx), e1 = __expf(s[1] - mx);
        float sum = e0 + e1;
#pragma unroll
        for (int d = 1; d < 32; d <<= 1) sum += __shfl_xor(sum, d);
        float inv = 1.f / sum;
        psL[h * 68 + jj] = e0 * inv;
        psL[h * 68 + jj + 32] = e1 * inv;
    }
    __syncthreads();
    if (tid < 128) {
        int h = tid >> 4, d = tid & 15, hc = h * 16;
        float a = 0.f;
#pragma unroll 4
        for (int j0 = 0; j0 < 64; j0 += 4) {
            float4 p4 = *(const float4*)&psL[h * 68 + j0];
            short4_t v4 = *(const short4_t*)&vT[(hc + d) * 68 + j0];
            a += p4.x * b2f((ushort_t)v4[0]) + p4.y * b2f((ushort_t)v4[1])
               + p4.z * b2f((ushort_t)v4[2]) + p4.w * b2f((ushort_t)v4[3]);
        }
        o1[(size_t)gid * 128 + hc + d] = f2b(a);
    }
}

// ---------------------------------------------------------------------------
// K2 (round-5 structure widened to 512 thr = 8 waves): per b, 16 blocks.
// Column split 8-ways (CT=1 / CT=2 for FF); attention: wave = one head,
// 4 iterations x 32 query rows. Same barrier structure as round 5.
// ---------------------------------------------------------------------------
__global__ __launch_bounds__(512, 1) void k2_tail(
    const int* __restrict__ lens, const ushort_t* __restrict__ wt,
    const ushort_t* __restrict__ o1, const float* __restrict__ xr0f,
    const float* __restrict__ bq, const float* __restrict__ bk,
    const float* __restrict__ bv, const float* __restrict__ bo,
    const float* __restrict__ l1s, const float* __restrict__ l1b,
    const float* __restrict__ b1, const float* __restrict__ b2,
    const float* __restrict__ l2s, const float* __restrict__ l2b,
    float* __restrict__ outp)
{
    __shared__ ushort_t pool[69632];
    __shared__ float redL[2048];
    __shared__ int vld[128];
    ushort_t* yL = pool;             // [128][136]
    ushort_t* qL = pool + 17408;     // [128][136] (o in-place)
    ushort_t* kL = pool + 34816;     // [128][136]
    ushort_t* vT = pool + 52224;     // [128][136] transposed
    ushort_t* hL = pool + 34816;     // [128][272] overlays kL+vT

    const int tid = threadIdx.x, lane = tid & 63, wv = tid >> 6;  // wv in [0,8)
    const int l15 = lane & 15, lq = lane >> 4;
    const int b = blockIdx.x;
    const int cb1 = wv * 16;         // colbase for CT=1 (128-wide outputs)
    const int cb2 = wv * 32;         // colbase for CT=2 (256-wide FF)

    if (tid < 128) vld[tid] = (lens[b * 128 + tid] > 0) ? 1 : 0;
    // stage o1 block rows -> kL
#pragma unroll
    for (int it = 0; it < 4; ++it) {
        int e = tid + it * 512;
        int row = e >> 4, cg = e & 15;
        *(short8*)&kL[row * 136 + cg * 8] =
            *(const short8*)&o1[((size_t)b * 128 + row) * 128 + cg * 8];
    }
    __syncthreads();

    floatx4 a1[8][1];
    float yre[8][1][4];

    // ---- L1 o-proj + resid(global fp32 xr0f) + LN -> yre, yL ----
    mm_g<8, 1, 128>(kL, 136, wt + OFFO(1), cb1, lane, a1);
    add_bias<8, 1>(a1, bo + 128, cb1, l15);
#pragma unroll
    for (int r = 0; r < 8; ++r)
#pragma unroll
        for (int gg = 0; gg < 4; ++gg) {
            int row = r * 16 + lq * 4 + gg;
            a1[r][0][gg] += xr0f[((size_t)b * 128 + row) * 128 + cb1 + l15];
        }
    ln_norm<8, 1, 8>(a1, redL, l1s + 128, l1b + 128, cb1, l15, lq, wv);
    save_resid<8, 1>(yre, a1);
    st_n<8, 1>(a1, yL, 136, cb1, l15, lq);
    __syncthreads();
    // ---- L1 FFN ----
    {
        floatx4 aw[8][2];
        mm_g<8, 2, 128>(yL, 136, wt + OFFW1(1), cb2, lane, aw);
        add_bias<8, 2>(aw, b1 + FF_, cb2, l15);
#pragma unroll
        for (int r = 0; r < 8; ++r)
#pragma unroll
            for (int c = 0; c < 2; ++c)
#pragma unroll
                for (int gg = 0; gg < 4; ++gg) aw[r][c][gg] = fmaxf(aw[r][c][gg], 0.f);
        st_n<8, 2>(aw, hL, 272, cb2, l15, lq);
    }
    __syncthreads();
    mm_g<8, 1, 256>(hL, 272, wt + OFFW2(1), cb1, lane, a1);
    add_bias<8, 1>(a1, b2 + 128, cb1, l15);
    add_resid_reg<8, 1>(a1, yre);
    ln_norm<8, 1, 8>(a1, redL, l2s + 128, l2b + 128, cb1, l15, lq, wv);
    save_resid<8, 1>(yre, a1);
    st_n<8, 1>(a1, yL, 136, cb1, l15, lq);
    __syncthreads();

    // j-validity bitmask for this lane (same for both spatial layers)
    unsigned jm = 0;
#pragma unroll
    for (int jt = 0; jt < 8; ++jt)
#pragma unroll
        for (int gg = 0; gg < 4; ++gg)
            if (vld[jt * 16 + lq * 4 + gg]) jm |= (1u << (jt * 4 + gg));

    // ---- spatial layers 2,3 ----
    for (int l = 2; l < 4; ++l) {
        // QKV
        mm_g<8, 1, 128>(yL, 136, wt + OFFQ(l), cb1, lane, a1);
        add_bias<8, 1>(a1, bq + l * 128, cb1, l15);
        st_n<8, 1>(a1, qL, 136, cb1, l15, lq);
        mm_g<8, 1, 128>(yL, 136, wt + OFFK(l), cb1, lane, a1);
        add_bias<8, 1>(a1, bk + l * 128, cb1, l15);
        st_n<8, 1>(a1, kL, 136, cb1, l15, lq);
        mm_g<8, 1, 128>(yL, 136, wt + OFFV(l), cb1, lane, a1);
        add_bias<8, 1>(a1, bv + l * 128, cb1, l15);
        st_t<8, 1>(a1, vT, 136, cb1, l15, lq);
        __syncthreads();
        // attention: wave = head wv; 4 iterations x 32 query rows
        {
            const int hc = wv * 16;
#pragma unroll
            for (int it = 0; it < 4; ++it) {
                const int i0 = it * 32 + l15, i1 = i0 + 16;
                const bool iv0 = vld[i0] != 0, iv1 = vld[i1] != 0;
                short8 z8 = {0, 0, 0, 0, 0, 0, 0, 0};
                short8 bqa = z8, bqb = z8;
                if (lq < 2) {
                    bqa = *(const short8*)&qL[i0 * 136 + hc + lq * 8];
                    bqb = *(const short8*)&qL[i1 * 136 + hc + lq * 8];
                }
                floatx4 s0[8], s1[8];
#pragma unroll
                for (int jt = 0; jt < 8; ++jt) {
                    short8 ak = z8;
                    if (lq < 2) ak = *(const short8*)&kL[(jt * 16 + l15) * 136 + hc + lq * 8];
                    floatx4 zz = {0.f, 0.f, 0.f, 0.f};
                    s0[jt] = __builtin_amdgcn_mfma_f32_16x16x32_bf16(ak, bqa, zz, 0, 0, 0);
                    s1[jt] = __builtin_amdgcn_mfma_f32_16x16x32_bf16(ak, bqb, zz, 0, 0, 0);
                }
                int px0[8][2], px1[8][2];
                softmax_pack<8>(s0, iv0, jm, px0);
                softmax_pack<8>(s1, iv1, jm, px1);
                floatx4 o0 = {0.f, 0.f, 0.f, 0.f}, o1a = {0.f, 0.f, 0.f, 0.f};
#pragma unroll
                for (int jc = 0; jc < 4; ++jc) {
                    short8 av = vfrag(vT, 136, hc + l15, jc * 32 + lq * 8);
                    o0 = __builtin_amdgcn_mfma_f32_16x16x32_bf16(av, pfrag(px0, jc, lq, l15), o0, 0, 0, 0);
                    o1a = __builtin_amdgcn_mfma_f32_16x16x32_bf16(av, pfrag(px1, jc, lq, l15), o1a, 0, 0, 0);
                }
                short4_t w0, w1;
#pragma unroll
                for (int gg = 0; gg < 4; ++gg) { w0[gg] = (short)f2b(o0[gg]); w1[gg] = (short)f2b(o1a[gg]); }
                *(short4_t*)&qL[i0 * 136 + hc + lq * 4] = w0;
                *(short4_t*)&qL[i1 * 136 + hc + lq * 4] = w1;
            }
        }
        __syncthreads();
        // O-proj + resid + LN -> yre, yL
        mm_g<8, 1, 128>(qL, 136, wt + OFFO(l), cb1, lane, a1);
        add_bias<8, 1>(a1, bo + l * 128, cb1, l15);
        add_resid_reg<8, 1>(a1, yre);
        ln_norm<8, 1, 8>(a1, redL, l1s + l * 128, l1b + l * 128, cb1, l15, lq, wv);
        save_resid<8, 1>(yre, a1);
        st_n<8, 1>(a1, yL, 136, cb1, l15, lq);
        __syncthreads();
        // FFN
        {
            floatx4 aw[8][2];
            mm_g<8, 2, 128>(yL, 136, wt + OFFW1(l), cb2, lane, aw);
            add_bias<8, 2>(aw, b1 + l * FF_, cb2, l15);
#pragma unroll
            for (int r = 0; r < 8; ++r)
#pragma unroll
                for (int c = 0; c < 2; ++c)
#pragma unroll
                    for (int gg = 0; gg < 4; ++gg) aw[r][c][gg] = fmaxf(aw[r][c][gg], 0.f);
            st_n<8, 2>(aw, hL, 272, cb2, l15, lq);
        }
        __syncthreads();
        mm_g<8, 1, 256>(hL, 272, wt + OFFW2(l), cb1, lane, a1);
        add_bias<8, 1>(a1, b2 + l * 128, cb1, l15);
        add_resid_reg<8, 1>(a1, yre);
        ln_norm<8, 1, 8>(a1, redL, l2s + l * 128, l2b + l * 128, cb1, l15, lq, wv);
        if (l == 3) {
#pragma unroll
            for (int r = 0; r < 4; ++r)     // only rows < 64 survive
#pragma unroll
                for (int gg = 0; gg < 4; ++gg) {
                    int row = r * 16 + lq * 4 + gg;
                    outp[(size_t)b * 8192 + row * 128 + cb1 + l15] = a1[r][0][gg];
                }
        } else {
            save_resid<8, 1>(yre, a1);
            st_n<8, 1>(a1, yL, 136, cb1, l15, lq);
        }
        __syncthreads();
    }
}

// ---------------------------------------------------------------------------
extern "C" void kernel_launch(void* const* d_in, const int* in_sizes, int n_in,
                              void* d_out, int out_size, void* d_ws, size_t ws_size,
                              hipStream_t stream)
{
    const float* poly   = (const float*)d_in[0];
    const int*   lens   = (const int*)d_in[1];
    const float* proj_w = (const float*)d_in[2];
    const float* proj_b = (const float*)d_in[3];
    const float* pls    = (const float*)d_in[4];
    const float* plb    = (const float*)d_in[5];
    const float* pos    = (const float*)d_in[6];
    const float* Wq = (const float*)d_in[7];
    const float* bq = (const float*)d_in[8];
    const float* Wk = (const float*)d_in[9];
    const float* bk = (const float*)d_in[10];
    const float* Wv = (const float*)d_in[11];
    const float* bv = (const float*)d_in[12];
    const float* Wo = (const float*)d_in[13];
    const float* bo = (const float*)d_in[14];
    const float* l1s = (const float*)d_in[15];
    const float* l1b = (const float*)d_in[16];
    const float* W1 = (const float*)d_in[17];
    const float* b1 = (const float*)d_in[18];
    const float* W2 = (const float*)d_in[19];
    const float* b2 = (const float*)d_in[20];
    const float* l2s = (const float*)d_in[21];
    const float* l2b = (const float*)d_in[22];
    float* outp = (float*)d_out;

    char* base = (char*)d_ws;
    ushort_t* wt    = (ushort_t*)base;                 // 540672 bf16
    ushort_t* o1buf = (ushort_t*)(base + 1081344);     // [2048][128] bf16
    float* xr0f     = (float*)(base + 1605632);        // [2048][128] fp32

    const int HH = H_ * H_, HF = H_ * FF_;
    WtArgs wa;
    wa.e[0] = {proj_w, 128, 128, 2, OFFP};
    for (int l = 0; l < 4; ++l) {
        wa.e[1 + l * 4 + 0] = {Wq + l * HH, 128, 128, 2, OFFQ(l)};
        wa.e[1 + l * 4 + 1] = {Wk + l * HH, 128, 128, 2, OFFK(l)};
        wa.e[1 + l * 4 + 2] = {Wv + l * HH, 128, 128, 2, OFFV(l)};
        wa.e[1 + l * 4 + 3] = {Wo + l * HH, 128, 128, 2, OFFO(l)};
    }
    for (int l = 0; l < 4; ++l) {
        wa.e[17 + l * 2 + 0] = {W1 + l * HF, 256, 128, 3, OFFW1(l)};
        wa.e[17 + l * 2 + 1] = {W2 + l * HF, 128, 256, 2, OFFW2(l)};
    }
    wt_kernel<<<dim3(25, 32), 256, 0, stream>>>(wa, wt);

    k1_mega<<<dim3(2048), 256, 0, stream>>>(
        poly, lens, wt,
        proj_b, pls, plb, pos,
        bq, bk, bv, bo, l1s, l1b, b1, b2, l2s, l2b,
        bq + H_, bk + H_, bv + H_,
        o1buf, xr0f);

    k2_tail<<<dim3(16), 512, 0, stream>>>(
        lens, wt, o1buf, xr0f,
        bq, bk, bv, bo, l1s, l1b, b1, b2, l2s, l2b,
        outp);
}

// Round 10
// 432.027 us; speedup vs baseline: 1.4815x; 1.4815x over previous
//
#include <hip/hip_runtime.h>

typedef short short8 __attribute__((ext_vector_type(8)));
typedef short short4_t __attribute__((ext_vector_type(4)));
typedef float floatx4 __attribute__((ext_vector_type(4)));
typedef unsigned short ushort_t;

#define B_ 16
#define S_ 128
#define T_ 64
#define H_ 128
#define FF_ 256
#define SCALEQK 0.25f

#define EPI_BIAS 0
#define EPI_RELU 1
#define EPI_LNRES 2
#define EPI_PROJ 3

// bf16 transposed-weight pool offsets (ushort units)
#define OFFP 0
#define OFFQ(l) (16384 + (l) * 65536)
#define OFFK(l) (OFFQ(l) + 16384)
#define OFFV(l) (OFFQ(l) + 32768)
#define OFFO(l) (OFFQ(l) + 49152)
#define OFFW1(l) (278528 + (l) * 65536)
#define OFFW2(l) (OFFW1(l) + 32768)

__device__ __forceinline__ float b2f(ushort_t u) {
    union { unsigned int i; float f; } x; x.i = ((unsigned int)u) << 16; return x.f;
}
__device__ __forceinline__ ushort_t f2b(float f) {
    union { float f; unsigned int i; } x; x.f = f;
    unsigned int r = x.i + 0x7fffu + ((x.i >> 16) & 1u);
    return (ushort_t)(r >> 16);
}
__device__ __forceinline__ int pack2b(float a, float b) {
    return (int)f2b(a) | ((int)f2b(b) << 16);
}

// ---------------------------------------------------------------------------
// Weight preconvert: fp32 W[K][N] -> bf16 wT[N][K] (round-2 proven).
// ---------------------------------------------------------------------------
struct WtEnt { const float* src; int N; int K; int nclog2; int dstoff; };
struct WtArgs { WtEnt e[25]; };

__global__ __launch_bounds__(256) void wt_kernel(WtArgs a, ushort_t* __restrict__ dst) {
    WtEnt ent = a.e[blockIdx.x];
    const int tiles_c = ent.N >> 5;
    const int nt = (ent.K >> 5) * tiles_c;
    const int t = blockIdx.y;
    if (t >= nt) return;
    const int tc = t & (tiles_c - 1);
    const int tr = t >> ent.nclog2;
    __shared__ float ld[32 * 33];
    const int tid = threadIdx.x;
#pragma unroll
    for (int i = 0; i < 4; ++i) {
        int e = tid + i * 256;
        int rr = e >> 5, cc = e & 31;
        ld[rr * 33 + cc] = ent.src[(tr * 32 + rr) * ent.N + tc * 32 + cc];
    }
    __syncthreads();
    ushort_t* d = dst + ent.dstoff;
#pragma unroll
    for (int i = 0; i < 4; ++i) {
        int e = tid + i * 256;
        int rr = e >> 5, cc = e & 31;
        d[(tc * 32 + rr) * ent.K + tr * 32 + cc] = f2b(ld[cc * 33 + rr]);
    }
}

// ---------------------------------------------------------------------------
// Round-2 proven standalone MFMA GEMM + epilogues (verbatim).
// ---------------------------------------------------------------------------
template<int K, int EPI, bool PAD, bool FINAL, bool MULTI, bool OUTB, bool AB16>
__global__ __launch_bounds__(256, 2) void gemm_mfma(
    const void* __restrict__ Av, int lda,
    const ushort_t* wt0, const ushort_t* wt1, const ushort_t* wt2,
    const float* b0, const float* b1, const float* b2,
    const float* __restrict__ resid, int rstride,
    const float* __restrict__ lns, const float* __restrict__ lnb,
    const float* __restrict__ pos, const int* __restrict__ lens,
    void* o0, void* o1, void* o2,
    int Ntot)
{
    __shared__ ushort_t aL[128 * 136];
    __shared__ ushort_t wL[128 * 136];

    const int tid = threadIdx.x;
    const int lane = tid & 63, wv = tid >> 6;
    const size_t rowbase = (size_t)blockIdx.x * 128;

    const ushort_t* wT; const float* bias; void* out; int cbase;
    if (MULTI) {
        int sel = blockIdx.y;
        wT = sel == 0 ? wt0 : (sel == 1 ? wt1 : wt2);
        bias = sel == 0 ? b0 : (sel == 1 ? b1 : b2);
        out = sel == 0 ? o0 : (sel == 1 ? o1 : o2);
        cbase = 0;
    } else {
        wT = wt0; bias = b0; out = o0; cbase = blockIdx.y * 128;
    }

    floatx4 acc[2][8];
#pragma unroll
    for (int a = 0; a < 2; ++a)
#pragma unroll
        for (int c = 0; c < 8; ++c) acc[a][c] = (floatx4){0.f, 0.f, 0.f, 0.f};

    const int arow = wv * 32 + (lane & 15);
    const int koff = (lane >> 4) * 8;

    for (int kc = 0; kc < K; kc += 128) {
        if (kc) __syncthreads();
        // ---- stage A (convert to bf16) ----
#pragma unroll
        for (int it = 0; it < 8; ++it) {
            int e8 = tid + it * 256;
            int row = e8 >> 4, kg = e8 & 15;
            int kk = kc + kg * 8;
            short8 val;
            if (AB16) {
                val = *(const short8*)((const ushort_t*)Av + (size_t)(rowbase + row) * lda + kk);
            } else {
                const float* Af = (const float*)Av + (size_t)(rowbase + row) * lda + kk;
                float f[8];
                *(float4*)(f) = *(const float4*)(Af);
                *(float4*)(f + 4) = *(const float4*)(Af + 4);
                if (PAD) {
                    int r = (int)(rowbase + row);
                    if ((r & 63) >= lens[r >> 6]) {
#pragma unroll
                        for (int q = 0; q < 8; ++q) f[q] = -1.0f;
                    }
                }
#pragma unroll
                for (int q = 0; q < 8; ++q) val[q] = (short)f2b(f[q]);
            }
            *(short8*)&aL[row * 136 + kg * 8] = val;
        }
        // ---- stage W ----
#pragma unroll
        for (int it = 0; it < 8; ++it) {
            int e8 = tid + it * 256;
            int n = e8 >> 4, kg = e8 & 15;
            *(short8*)&wL[n * 136 + kg * 8] =
                *(const short8*)&wT[(size_t)(cbase + n) * K + kc + kg * 8];
        }
        __syncthreads();
        // ---- mfma ----
#pragma unroll
        for (int k0 = 0; k0 < 128; k0 += 32) {
            short8 a0 = *(const short8*)&aL[arow * 136 + k0 + koff];
            short8 a1 = *(const short8*)&aL[(arow + 16) * 136 + k0 + koff];
#pragma unroll
            for (int ct = 0; ct < 8; ++ct) {
                short8 b = *(const short8*)&wL[(ct * 16 + (lane & 15)) * 136 + k0 + koff];
                acc[0][ct] = __builtin_amdgcn_mfma_f32_16x16x32_bf16(a0, b, acc[0][ct], 0, 0, 0);
                acc[1][ct] = __builtin_amdgcn_mfma_f32_16x16x32_bf16(a1, b, acc[1][ct], 0, 0, 0);
            }
        }
    }

    // ---- epilogue ----
    const int col16 = lane & 15;
    const int rgrp = (lane >> 4) * 4;
    float bcol[8], lnsc[8], lnbc[8];
#pragma unroll
    for (int ct = 0; ct < 8; ++ct) bcol[ct] = bias[cbase + ct * 16 + col16];
    if (EPI == EPI_LNRES || EPI == EPI_PROJ) {
#pragma unroll
        for (int ct = 0; ct < 8; ++ct) {
            lnsc[ct] = lns[ct * 16 + col16];
            lnbc[ct] = lnb[ct * 16 + col16];
        }
    }

#pragma unroll
    for (int rt = 0; rt < 2; ++rt) {
        const int rbase = wv * 32 + rt * 16 + rgrp;
#pragma unroll
        for (int ct = 0; ct < 8; ++ct)
#pragma unroll
            for (int rg = 0; rg < 4; ++rg) {
                float v = acc[rt][ct][rg] + bcol[ct];
                if (EPI == EPI_LNRES)
                    v += resid[(rowbase + rbase + rg) * (size_t)rstride + ct * 16 + col16];
                acc[rt][ct][rg] = v;
            }
        if (EPI == EPI_LNRES || EPI == EPI_PROJ) {
            float mean[4], rstd[4];
#pragma unroll
            for (int rg = 0; rg < 4; ++rg) {
                float s = 0.f;
#pragma unroll
                for (int ct = 0; ct < 8; ++ct) s += acc[rt][ct][rg];
                s += __shfl_xor(s, 1); s += __shfl_xor(s, 2);
                s += __shfl_xor(s, 4); s += __shfl_xor(s, 8);
                mean[rg] = s * (1.f / 128.f);
            }
#pragma unroll
            for (int rg = 0; rg < 4; ++rg) {
                float s = 0.f;
#pragma unroll
                for (int ct = 0; ct < 8; ++ct) {
                    float d = acc[rt][ct][rg] - mean[rg];
                    s += d * d;
                }
                s += __shfl_xor(s, 1); s += __shfl_xor(s, 2);
                s += __shfl_xor(s, 4); s += __shfl_xor(s, 8);
                rstd[rg] = rsqrtf(s * (1.f / 128.f) + 1e-5f);
            }
#pragma unroll
            for (int ct = 0; ct < 8; ++ct)
#pragma unroll
                for (int rg = 0; rg < 4; ++rg)
                    acc[rt][ct][rg] = (acc[rt][ct][rg] - mean[rg]) * rstd[rg] * lnsc[ct] + lnbc[ct];
        }
#pragma unroll
        for (int ct = 0; ct < 8; ++ct)
#pragma unroll
            for (int rg = 0; rg < 4; ++rg) {
                size_t grow = rowbase + rbase + rg;
                int col = cbase + ct * 16 + col16;
                float v = acc[rt][ct][rg];
                if (EPI == EPI_RELU) v = fmaxf(v, 0.f);
                if (EPI == EPI_PROJ)
                    v = fmaxf(v, 0.f) + pos[((int)grow & 63) * H_ + ct * 16 + col16];
                if (FINAL) {
                    int b = (int)(grow >> 7), s = (int)(grow & 127);
                    if (s < T_) ((float*)out)[((size_t)(b * T_ + s)) * H_ + col] = v;
                } else if (OUTB) {
                    ((ushort_t*)out)[grow * (size_t)Ntot + col] = f2b(v);
                } else {
                    ((float*)out)[grow * (size_t)Ntot + col] = v;
                }
            }
    }
}

// ---------------------------------------------------------------------------
// Round-2 proven spatial attention, L=128. Block = (b, head-pair).
// 256 thr = 2 heads x 128 rows.
// ---------------------------------------------------------------------------
__global__ __launch_bounds__(256, 1) void attn_s(
    ushort_t* qo, const ushort_t* __restrict__ kk, const ushort_t* __restrict__ vv,
    const int* __restrict__ lens)
{
    __shared__ float kL[128 * 36];
    __shared__ float vL[128 * 36];
    __shared__ int vldL[128];
    const int tid = threadIdx.x;
    const int b = blockIdx.x, hp = blockIdx.y;
    const size_t rowg = (size_t)b * 128;

    if (tid < 128) vldL[tid] = (lens[b * 128 + tid] > 0) ? 1 : 0;
#pragma unroll
    for (int it = 0; it < 2; ++it) {
        int e8 = tid + it * 256;
        int j = e8 >> 2, dg = e8 & 3;
        short8 k8 = *(const short8*)&kk[(rowg + j) * 128 + hp * 32 + dg * 8];
        short8 v8 = *(const short8*)&vv[(rowg + j) * 128 + hp * 32 + dg * 8];
        float* kd = &kL[j * 36 + dg * 8];
        float* vd = &vL[j * 36 + dg * 8];
#pragma unroll
        for (int q = 0; q < 8; ++q) { kd[q] = b2f((ushort_t)k8[q]); vd[q] = b2f((ushort_t)v8[q]); }
    }
    __syncthreads();

    const int hl = tid >> 7;
    const int i = tid & 127;
    const int hc = hl * 16;
    const int h = hp * 2 + hl;

    float qf[16];
    {
        const short8* qp = (const short8*)&qo[(rowg + i) * 128 + h * 16];
        short8 q0 = qp[0], q1 = qp[1];
#pragma unroll
        for (int q = 0; q < 8; ++q) { qf[q] = b2f((ushort_t)q0[q]); qf[8 + q] = b2f((ushort_t)q1[q]); }
    }

    float sc[128];
    const bool iv = vldL[i] != 0;
#pragma unroll
    for (int j = 0; j < 128; ++j) {
        const float* kr = &kL[j * 36 + hc];
        float s = 0.f;
#pragma unroll
        for (int d = 0; d < 16; ++d) s = fmaf(qf[d], kr[d], s);
        sc[j] = (iv && vldL[j]) ? s * SCALEQK : -1e9f;
    }
    float m = -3.0e38f;
#pragma unroll
    for (int j = 0; j < 128; ++j) m = fmaxf(m, sc[j]);
    float sum = 0.f;
#pragma unroll
    for (int j = 0; j < 128; ++j) { float e = __expf(sc[j] - m); sc[j] = e; sum += e; }
    const float inv = 1.0f / sum;
    float of[16];
#pragma unroll
    for (int d = 0; d < 16; ++d) of[d] = 0.f;
#pragma unroll
    for (int j = 0; j < 128; ++j) {
        float p = sc[j] * inv;
        const float* vr = &vL[j * 36 + hc];
#pragma unroll
        for (int d = 0; d < 16; ++d) of[d] = fmaf(p, vr[d], of[d]);
    }
    short8 o0v, o1v;
#pragma unroll
    for (int q = 0; q < 8; ++q) { o0v[q] = (short)f2b(of[q]); o1v[q] = (short)f2b(of[8 + q]); }
    short8* op = (short8*)&qo[(rowg + i) * 128 + h * 16];
    op[0] = o0v; op[1] = o1v;
}

// ---------------------------------------------------------------------------
// Round-5 proven helpers for k1 (original orientation, verbatim).
// ---------------------------------------------------------------------------
template<int RT, int CT, int KK>
__device__ __forceinline__ void mm_g(const ushort_t* aL, int sa,
                                     const ushort_t* __restrict__ wT,
                                     int colbase, int lane, floatx4 (&acc)[RT][CT]) {
    const int l15 = lane & 15, lq8 = (lane >> 4) * 8;
#pragma unroll
    for (int r = 0; r < RT; ++r)
#pragma unroll
        for (int c = 0; c < CT; ++c) acc[r][c] = (floatx4){0.f, 0.f, 0.f, 0.f};
#pragma unroll
    for (int k0 = 0; k0 < KK; k0 += 32) {
        short8 b[CT];
#pragma unroll
        for (int c = 0; c < CT; ++c)
            b[c] = *(const short8*)&wT[(colbase + c * 16 + l15) * KK + k0 + lq8];
#pragma unroll
        for (int r = 0; r < RT; ++r) {
            short8 a = *(const short8*)&aL[(r * 16 + l15) * sa + k0 + lq8];
#pragma unroll
            for (int c = 0; c < CT; ++c)
                acc[r][c] = __builtin_amdgcn_mfma_f32_16x16x32_bf16(a, b[c], acc[r][c], 0, 0, 0);
        }
    }
}

template<int RT, int CT>
__device__ __forceinline__ void add_bias(floatx4 (&acc)[RT][CT], const float* b,
                                         int colbase, int l15) {
#pragma unroll
    for (int c = 0; c < CT; ++c) {
        float bc = b[colbase + c * 16 + l15];
#pragma unroll
        for (int r = 0; r < RT; ++r)
#pragma unroll
            for (int g = 0; g < 4; ++g) acc[r][c][g] += bc;
    }
}

template<int RT, int CT>
__device__ __forceinline__ void add_resid_reg(floatx4 (&acc)[RT][CT],
                                              const float (&res)[RT][CT][4]) {
#pragma unroll
    for (int r = 0; r < RT; ++r)
#pragma unroll
        for (int c = 0; c < CT; ++c)
#pragma unroll
            for (int g = 0; g < 4; ++g) acc[r][c][g] += res[r][c][g];
}
template<int RT, int CT>
__device__ __forceinline__ void save_resid(float (&res)[RT][CT][4],
                                           const floatx4 (&acc)[RT][CT]) {
#pragma unroll
    for (int r = 0; r < RT; ++r)
#pragma unroll
        for (int c = 0; c < CT; ++c)
#pragma unroll
            for (int g = 0; g < 4; ++g) res[r][c][g] = acc[r][c][g];
}

template<int RT, int CT>
__device__ __forceinline__ void st_n(const floatx4 (&acc)[RT][CT], ushort_t* dst, int stride,
                                     int colbase, int l15, int lq) {
#pragma unroll
    for (int r = 0; r < RT; ++r)
#pragma unroll
        for (int g = 0; g < 4; ++g) {
            int row = r * 16 + lq * 4 + g;
#pragma unroll
            for (int c = 0; c < CT; ++c)
                dst[row * stride + colbase + c * 16 + l15] = f2b(acc[r][c][g]);
        }
}

template<int RT, int CT>
__device__ __forceinline__ void st_t(const floatx4 (&acc)[RT][CT], ushort_t* dst, int stride,
                                     int colbase, int l15, int lq) {
#pragma unroll
    for (int r = 0; r < RT; ++r)
#pragma unroll
        for (int c = 0; c < CT; ++c) {
            int d = colbase + c * 16 + l15;
            short4_t p;
#pragma unroll
            for (int g = 0; g < 4; ++g) p[g] = (short)f2b(acc[r][c][g]);
            *(short4_t*)&dst[d * stride + r * 16 + lq * 4] = p;
        }
}

template<int RT, int CT>
__device__ __forceinline__ void ln_norm(floatx4 (&acc)[RT][CT], float* redL,
                                        const float* lns, const float* lnb,
                                        int colbase, int l15, int lq, int wv) {
#pragma unroll
    for (int r = 0; r < RT; ++r)
#pragma unroll
        for (int g = 0; g < 4; ++g) {
            float s = 0.f, q = 0.f;
#pragma unroll
            for (int c = 0; c < CT; ++c) { float v = acc[r][c][g]; s += v; q += v * v; }
            s += __shfl_xor(s, 1); s += __shfl_xor(s, 2); s += __shfl_xor(s, 4); s += __shfl_xor(s, 8);
            q += __shfl_xor(q, 1); q += __shfl_xor(q, 2); q += __shfl_xor(q, 4); q += __shfl_xor(q, 8);
            if (l15 == 0) {
                int row = r * 16 + lq * 4 + g;
                redL[row * 8 + wv] = s;
                redL[row * 8 + 4 + wv] = q;
            }
        }
    __syncthreads();
#pragma unroll
    for (int r = 0; r < RT; ++r)
#pragma unroll
        for (int g = 0; g < 4; ++g) {
            int row = r * 16 + lq * 4 + g;
            float4 S = *(float4*)&redL[row * 8];
            float4 Q = *(float4*)&redL[row * 8 + 4];
            float mean = (S.x + S.y + S.z + S.w) * (1.f / 128.f);
            float var = (Q.x + Q.y + Q.z + Q.w) * (1.f / 128.f) - mean * mean;
            float rstd = rsqrtf(var + 1e-5f);
#pragma unroll
            for (int c = 0; c < CT; ++c) {
                int col = colbase + c * 16 + l15;
                acc[r][c][g] = (acc[r][c][g] - mean) * rstd * lns[col] + lnb[col];
            }
        }
}

template<int JT>
__device__ __forceinline__ void softmax_pack(floatx4 (&st)[JT], bool iv, unsigned jm,
                                             int (&px)[JT][2]) {
    float ev[JT][4];
    float mx = -3.0e38f;
#pragma unroll
    for (int jt = 0; jt < JT; ++jt)
#pragma unroll
        for (int g = 0; g < 4; ++g) {
            bool ok = iv && ((jm >> (jt * 4 + g)) & 1u);
            float s = ok ? st[jt][g] * SCALEQK : -1e9f;
            ev[jt][g] = s; mx = fmaxf(mx, s);
        }
    mx = fmaxf(mx, __shfl_xor(mx, 16)); mx = fmaxf(mx, __shfl_xor(mx, 32));
    float sum = 0.f;
#pragma unroll
    for (int jt = 0; jt < JT; ++jt)
#pragma unroll
        for (int g = 0; g < 4; ++g) { float e = __expf(ev[jt][g] - mx); ev[jt][g] = e; sum += e; }
    sum += __shfl_xor(sum, 16); sum += __shfl_xor(sum, 32);
    float inv = 1.f / sum;
#pragma unroll
    for (int jt = 0; jt < JT; ++jt) {
        px[jt][0] = pack2b(ev[jt][0] * inv, ev[jt][1] * inv);
        px[jt][1] = pack2b(ev[jt][2] * inv, ev[jt][3] * inv);
    }
}

__device__ __forceinline__ short8 pfrag(const int (*px)[2], int jc, int lq, int l15) {
    const int jA = (lq & 1) * 32 + l15;
    int a0 = __shfl(px[jc * 2][0], jA);
    int a1 = __shfl(px[jc * 2][1], jA);
    int a2 = __shfl(px[jc * 2][0], jA + 16);
    int a3 = __shfl(px[jc * 2][1], jA + 16);
    int b0 = __shfl(px[jc * 2 + 1][0], jA);
    int b1 = __shfl(px[jc * 2 + 1][1], jA);
    int b2 = __shfl(px[jc * 2 + 1][0], jA + 16);
    int b3 = __shfl(px[jc * 2 + 1][1], jA + 16);
    const bool t = (lq >> 1) != 0;
    union { int4 i; short8 s; } u;
    u.i = make_int4(t ? b0 : a0, t ? b1 : a1, t ? b2 : a2, t ? b3 : a3);
    return u.s;
}
__device__ __forceinline__ short8 vfrag(const ushort_t* vT, int stride, int row, int off) {
    int2 a = *(const int2*)&vT[row * stride + off];
    int2 b = *(const int2*)&vT[row * stride + off + 4];
    union { int4 i; short8 s; } u;
    u.i = make_int4(a.x, a.y, b.x, b.y);
    return u.s;
}

// ---------------------------------------------------------------------------
// K1 (round-5 proven, verbatim): per group gid (64 rows): input proj -> L0
// full -> L1 (kv + q@t0 + attn). Writes o1[gid][128] bf16 + xr0f[gid][128]
// fp32. 2048 blocks x 256 thr.
// ---------------------------------------------------------------------------
__global__ __launch_bounds__(256, 2) void k1_mega(
    const float* __restrict__ poly, const int* __restrict__ lens,
    const ushort_t* __restrict__ wt,
    const float* __restrict__ projb, const float* __restrict__ pls,
    const float* __restrict__ plb, const float* __restrict__ pos,
    const float* __restrict__ bq0, const float* __restrict__ bk0,
    const float* __restrict__ bv0, const float* __restrict__ bo0,
    const float* __restrict__ l1s0, const float* __restrict__ l1b0,
    const float* __restrict__ b10, const float* __restrict__ b20,
    const float* __restrict__ l2s0, const float* __restrict__ l2b0,
    const float* __restrict__ bq1, const float* __restrict__ bk1,
    const float* __restrict__ bv1,
    ushort_t* __restrict__ o1, float* __restrict__ xr0f)
{
    __shared__ ushort_t pool[34816];
    __shared__ float redL[512];
    __shared__ float psL[8 * 68];
    __shared__ float q1L[128];
    ushort_t* xL = pool;            // [64][136]
    ushort_t* qL = pool + 8704;     // [64][136]  (o written in-place per head)
    ushort_t* kL = pool + 17408;    // [64][136]
    ushort_t* vT = pool + 26112;    // [128][68]  v transposed
    ushort_t* hL = pool + 17408;    // [64][272]  FFN hidden, overlays kL+vT

    const int tid = threadIdx.x, lane = tid & 63, wv = tid >> 6;
    const int l15 = lane & 15, lq = lane >> 4;
    const int gid = blockIdx.x;
    const int len = lens[gid];

    // ---- stage poly -> xL (bf16, -1 pad) ----
    {
        const float* pg = poly + (size_t)gid * 8192;
#pragma unroll
        for (int it = 0; it < 8; ++it) {
            int e4 = (tid + it * 256) * 4;
            int row = e4 >> 7, col = e4 & 127;
            float4 f = *(const float4*)(pg + e4);
            if (row >= len) { f.x = -1.f; f.y = -1.f; f.z = -1.f; f.w = -1.f; }
            short4_t u;
            u[0] = (short)f2b(f.x); u[1] = (short)f2b(f.y);
            u[2] = (short)f2b(f.z); u[3] = (short)f2b(f.w);
            *(short4_t*)&xL[row * 136 + col] = u;
        }
    }
    __syncthreads();

    floatx4 a2[4][2];
    float xre[4][2][4];             // fp32 residual stream (this thread's slice)

    // ---- P1: input proj + LN + relu + pos -> xre, xL ----
    mm_g<4, 2, 128>(xL, 136, wt + OFFP, wv * 32, lane, a2);
    add_bias<4, 2>(a2, projb, wv * 32, l15);
    ln_norm<4, 2>(a2, redL, pls, plb, wv * 32, l15, lq, wv);
    __syncthreads();               // done reading xL (staged poly) before overwrite
#pragma unroll
    for (int r = 0; r < 4; ++r)
#pragma unroll
        for (int gg = 0; gg < 4; ++gg) {
            int row = r * 16 + lq * 4 + gg;
#pragma unroll
            for (int c = 0; c < 2; ++c) {
                int col = wv * 32 + c * 16 + l15;
                float v = fmaxf(a2[r][c][gg], 0.f) + pos[row * 128 + col];
                xre[r][c][gg] = v;
                xL[row * 136 + col] = f2b(v);
            }
        }
    __syncthreads();

    // ---- P2: L0 QKV ----
    mm_g<4, 2, 128>(xL, 136, wt + OFFQ(0), wv * 32, lane, a2);
    add_bias<4, 2>(a2, bq0, wv * 32, l15);
    st_n<4, 2>(a2, qL, 136, wv * 32, l15, lq);
    mm_g<4, 2, 128>(xL, 136, wt + OFFK(0), wv * 32, lane, a2);
    add_bias<4, 2>(a2, bk0, wv * 32, l15);
    st_n<4, 2>(a2, kL, 136, wv * 32, l15, lq);
    mm_g<4, 2, 128>(xL, 136, wt + OFFV(0), wv * 32, lane, a2);
    add_bias<4, 2>(a2, bv0, wv * 32, l15);
    st_t<4, 2>(a2, vT, 68, wv * 32, l15, lq);
    __syncthreads();

    // ---- P3: L0 attention (MFMA S^T, reg softmax, shuffle-PV) ----
    {
        const int iRow = wv * 16 + l15;
        const bool iv = iRow < len;
        unsigned jm = 0;
#pragma unroll
        for (int jt = 0; jt < 4; ++jt)
#pragma unroll
            for (int gg = 0; gg < 4; ++gg)
                if (jt * 16 + lq * 4 + gg < len) jm |= (1u << (jt * 4 + gg));
        for (int h = 0; h < 8; ++h) {
            const int hc = h * 16;
            short8 z8 = {0, 0, 0, 0, 0, 0, 0, 0};
            short8 bqf = z8;
            if (lq < 2) bqf = *(const short8*)&qL[iRow * 136 + hc + lq * 8];
            floatx4 st[4];
#pragma unroll
            for (int jt = 0; jt < 4; ++jt) {
                short8 ak = z8;
                if (lq < 2) ak = *(const short8*)&kL[(jt * 16 + l15) * 136 + hc + lq * 8];
                floatx4 zz = {0.f, 0.f, 0.f, 0.f};
                st[jt] = __builtin_amdgcn_mfma_f32_16x16x32_bf16(ak, bqf, zz, 0, 0, 0);
            }
            int px[4][2];
            softmax_pack<4>(st, iv, jm, px);
            floatx4 ao = {0.f, 0.f, 0.f, 0.f};
#pragma unroll
            for (int jc = 0; jc < 2; ++jc) {
                short8 av = vfrag(vT, 68, hc + l15, jc * 32 + lq * 8);
                short8 bp = pfrag(px, jc, lq, l15);
                ao = __builtin_amdgcn_mfma_f32_16x16x32_bf16(av, bp, ao, 0, 0, 0);
            }
            short4_t w;
#pragma unroll
            for (int gg = 0; gg < 4; ++gg) w[gg] = (short)f2b(ao[gg]);
            *(short4_t*)&qL[iRow * 136 + hc + lq * 4] = w;
        }
    }
    __syncthreads();

    // ---- P4: O-proj + resid + LN -> xre, xL ----
    mm_g<4, 2, 128>(qL, 136, wt + OFFO(0), wv * 32, lane, a2);
    add_bias<4, 2>(a2, bo0, wv * 32, l15);
    add_resid_reg<4, 2>(a2, xre);
    ln_norm<4, 2>(a2, redL, l1s0, l1b0, wv * 32, l15, lq, wv);
    save_resid<4, 2>(xre, a2);
    st_n<4, 2>(a2, xL, 136, wv * 32, l15, lq);
    __syncthreads();

    // ---- P5: FFN W1 + relu -> hL ----
    {
        floatx4 a4[4][4];
        mm_g<4, 4, 128>(xL, 136, wt + OFFW1(0), wv * 64, lane, a4);
        add_bias<4, 4>(a4, b10, wv * 64, l15);
#pragma unroll
        for (int r = 0; r < 4; ++r)
#pragma unroll
            for (int c = 0; c < 4; ++c)
#pragma unroll
                for (int gg = 0; gg < 4; ++gg) a4[r][c][gg] = fmaxf(a4[r][c][gg], 0.f);
        st_n<4, 4>(a4, hL, 272, wv * 64, l15, lq);
    }
    __syncthreads();

    // ---- P6: FFN W2 + resid + LN -> xre, xL; row0 -> xr0f (fp32) ----
    mm_g<4, 2, 256>(hL, 272, wt + OFFW2(0), wv * 32, lane, a2);
    add_bias<4, 2>(a2, b20, wv * 32, l15);
    add_resid_reg<4, 2>(a2, xre);
    ln_norm<4, 2>(a2, redL, l2s0, l2b0, wv * 32, l15, lq, wv);
    save_resid<4, 2>(xre, a2);
    st_n<4, 2>(a2, xL, 136, wv * 32, l15, lq);
    if (lq == 0) {
#pragma unroll
        for (int c = 0; c < 2; ++c)
            xr0f[(size_t)gid * 128 + wv * 32 + c * 16 + l15] = a2[0][c][0];   // row 0
    }
    __syncthreads();

    // ---- P7: L1 K,V (full) + q at t=0 ----
    mm_g<4, 2, 128>(xL, 136, wt + OFFK(1), wv * 32, lane, a2);
    add_bias<4, 2>(a2, bk1, wv * 32, l15);
    st_n<4, 2>(a2, kL, 136, wv * 32, l15, lq);
    mm_g<4, 2, 128>(xL, 136, wt + OFFV(1), wv * 32, lane, a2);
    add_bias<4, 2>(a2, bv1, wv * 32, l15);
    st_t<4, 2>(a2, vT, 68, wv * 32, l15, lq);
    if (tid < 128) {
        int d = tid;
        float a = bq1[d];
        const ushort_t* wq = wt + OFFQ(1) + d * 128;
#pragma unroll 4
        for (int j0 = 0; j0 < 128; j0 += 8) {
            short8 w8 = *(const short8*)&wq[j0];
            short8 x8 = *(const short8*)&xL[j0];
#pragma unroll
            for (int q = 0; q < 8; ++q)
                a = fmaf(b2f((ushort_t)x8[q]), b2f((ushort_t)w8[q]), a);
        }
        q1L[d] = a;
    }
    __syncthreads();

    // ---- P8: L1 single-query attention -> o1 ----
    {
        int h = tid >> 5, jj = tid & 31;
        int hc = h * 16;
        float s[2];
#pragma unroll
        for (int half = 0; half < 2; ++half) {
            int j = jj + half * 32;
            float a = 0.f;
            short8 k0v = *(const short8*)&kL[j * 136 + hc];
            short8 k1v = *(const short8*)&kL[j * 136 + hc + 8];
#pragma unroll
            for (int q = 0; q < 8; ++q) {
                a = fmaf(q1L[hc + q], b2f((ushort_t)k0v[q]), a);
                a = fmaf(q1L[hc + 8 + q], b2f((ushort_t)k1v[q]), a);
            }
            s[half] = (j < len) ? a * SCALEQK : -1e9f;
        }
        float mx = fmaxf(s[0], s[1]);
#pragma unroll
        for (int d = 1; d < 32; d <<= 1) mx = fmaxf(mx, __shfl_xor(mx, d));
        float e0 = __expf(s[0] - mx), e1 = __expf(s[1] - mx);
        float sum = e0 + e1;
#pragma unroll
        for (int d = 1; d < 32; d <<= 1) sum += __shfl_xor(sum, d);
        float inv = 1.f / sum;
        psL[h * 68 + jj] = e0 * inv;
        psL[h * 68 + jj + 32] = e1 * inv;
    }
    __syncthreads();
    if (tid < 128) {
        int h = tid >> 4, d = tid & 15, hc = h * 16;
        float a = 0.f;
#pragma unroll 4
        for (int j0 = 0; j0 < 64; j0 += 4) {
            float4 p4 = *(const float4*)&psL[h * 68 + j0];
            short4_t v4 = *(const short4_t*)&vT[(hc + d) * 68 + j0];
            a += p4.x * b2f((ushort_t)v4[0]) + p4.y * b2f((ushort_t)v4[1])
               + p4.z * b2f((ushort_t)v4[2]) + p4.w * b2f((ushort_t)v4[3]);
        }
        o1[(size_t)gid * 128 + hc + d] = f2b(a);
    }
}

// ---------------------------------------------------------------------------
extern "C" void kernel_launch(void* const* d_in, const int* in_sizes, int n_in,
                              void* d_out, int out_size, void* d_ws, size_t ws_size,
                              hipStream_t stream)
{
    const float* poly   = (const float*)d_in[0];
    const int*   lens   = (const int*)d_in[1];
    const float* proj_w = (const float*)d_in[2];
    const float* proj_b = (const float*)d_in[3];
    const float* pls    = (const float*)d_in[4];
    const float* plb    = (const float*)d_in[5];
    const float* pos    = (const float*)d_in[6];
    const float* Wq = (const float*)d_in[7];
    const float* bq = (const float*)d_in[8];
    const float* Wk = (const float*)d_in[9];
    const float* bk = (const float*)d_in[10];
    const float* Wv = (const float*)d_in[11];
    const float* bv = (const float*)d_in[12];
    const float* Wo = (const float*)d_in[13];
    const float* bo = (const float*)d_in[14];
    const float* l1s = (const float*)d_in[15];
    const float* l1b = (const float*)d_in[16];
    const float* W1 = (const float*)d_in[17];
    const float* b1 = (const float*)d_in[18];
    const float* W2 = (const float*)d_in[19];
    const float* b2 = (const float*)d_in[20];
    const float* l2s = (const float*)d_in[21];
    const float* l2b = (const float*)d_in[22];
    float* outp = (float*)d_out;

    char* base = (char*)d_ws;
    ushort_t* wt    = (ushort_t*)base;                 // 540672 bf16 = 1,081,344 B
    ushort_t* o1buf = (ushort_t*)(base + 1081344);     // [2048][128] bf16
    float* xr0f     = (float*)(base + 1605632);        // [2048][128] fp32
    float* ybuf     = (float*)(base + 2654208);        // [2048][128] fp32
    ushort_t* hsml  = (ushort_t*)(base + 3702784);     // [2048][256] bf16
    ushort_t* q2    = (ushort_t*)(base + 4751360);     // [2048][128] bf16
    ushort_t* k2b   = (ushort_t*)(base + 5275648);
    ushort_t* v2    = (ushort_t*)(base + 5799936);

    const int HH = H_ * H_, HF = H_ * FF_;
    WtArgs wa;
    wa.e[0] = {proj_w, 128, 128, 2, OFFP};
    for (int l = 0; l < 4; ++l) {
        wa.e[1 + l * 4 + 0] = {Wq + l * HH, 128, 128, 2, OFFQ(l)};
        wa.e[1 + l * 4 + 1] = {Wk + l * HH, 128, 128, 2, OFFK(l)};
        wa.e[1 + l * 4 + 2] = {Wv + l * HH, 128, 128, 2, OFFV(l)};
        wa.e[1 + l * 4 + 3] = {Wo + l * HH, 128, 128, 2, OFFO(l)};
    }
    for (int l = 0; l < 4; ++l) {
        wa.e[17 + l * 2 + 0] = {W1 + l * HF, 256, 128, 3, OFFW1(l)};
        wa.e[17 + l * 2 + 1] = {W2 + l * HF, 128, 256, 2, OFFW2(l)};
    }
    wt_kernel<<<dim3(25, 32), 256, 0, stream>>>(wa, wt);

    // ---- fused input-proj + L0 + L1(kv,q,attn) ----
    k1_mega<<<dim3(2048), 256, 0, stream>>>(
        poly, lens, wt,
        proj_b, pls, plb, pos,
        bq, bk, bv, bo, l1s, l1b, b1, b2, l2s, l2b,
        bq + H_, bk + H_, bv + H_,
        o1buf, xr0f);

    // ---- L1 tail (phase-split, round-2 kernels) ----
    gemm_mfma<128, EPI_LNRES, false, false, false, false, true><<<dim3(16, 1), 256, 0, stream>>>(
        o1buf, 128, wt + OFFO(1), wt + OFFO(1), wt + OFFO(1), bo + H_, bo + H_, bo + H_,
        xr0f, 128, l1s + H_, l1b + H_, nullptr, nullptr, ybuf, ybuf, ybuf, H_);
    gemm_mfma<128, EPI_RELU, false, false, false, true, false><<<dim3(16, 2), 256, 0, stream>>>(
        ybuf, 128, wt + OFFW1(1), wt + OFFW1(1), wt + OFFW1(1), b1 + FF_, b1 + FF_, b1 + FF_,
        nullptr, 0, nullptr, nullptr, nullptr, nullptr, hsml, hsml, hsml, FF_);
    gemm_mfma<256, EPI_LNRES, false, false, false, false, true><<<dim3(16, 1), 256, 0, stream>>>(
        hsml, 256, wt + OFFW2(1), wt + OFFW2(1), wt + OFFW2(1), b2 + H_, b2 + H_, b2 + H_,
        ybuf, 128, l2s + H_, l2b + H_, nullptr, nullptr, ybuf, ybuf, ybuf, H_);

    // ---- spatial layers 2,3 (phase-split, round-2 kernels) ----
    for (int l = 2; l < 4; ++l) {
        gemm_mfma<128, EPI_BIAS, false, false, true, true, false><<<dim3(16, 3), 256, 0, stream>>>(
            ybuf, 128, wt + OFFQ(l), wt + OFFK(l), wt + OFFV(l),
            bq + l * H_, bk + l * H_, bv + l * H_,
            nullptr, 0, nullptr, nullptr, nullptr, nullptr, q2, k2b, v2, H_);
        attn_s<<<dim3(16, 4), 256, 0, stream>>>(q2, k2b, v2, lens);
        gemm_mfma<128, EPI_LNRES, false, false, false, false, true><<<dim3(16, 1), 256, 0, stream>>>(
            q2, 128, wt + OFFO(l), wt + OFFO(l), wt + OFFO(l), bo + l * H_, bo + l * H_, bo + l * H_,
            ybuf, 128, l1s + l * H_, l1b + l * H_, nullptr, nullptr, ybuf, ybuf, ybuf, H_);
        gemm_mfma<128, EPI_RELU, false, false, false, true, false><<<dim3(16, 2), 256, 0, stream>>>(
            ybuf, 128, wt + OFFW1(l), wt + OFFW1(l), wt + OFFW1(l),
            b1 + l * FF_, b1 + l * FF_, b1 + l * FF_,
            nullptr, 0, nullptr, nullptr, nullptr, nullptr, hsml, hsml, hsml, FF_);
        if (l < 3) {
            gemm_mfma<256, EPI_LNRES, false, false, false, false, true><<<dim3(16, 1), 256, 0, stream>>>(
                hsml, 256, wt + OFFW2(l), wt + OFFW2(l), wt + OFFW2(l),
                b2 + l * H_, b2 + l * H_, b2 + l * H_,
                ybuf, 128, l2s + l * H_, l2b + l * H_, nullptr, nullptr, ybuf, ybuf, ybuf, H_);
        } else {
            gemm_mfma<256, EPI_LNRES, false, true, false, false, true><<<dim3(16, 1), 256, 0, stream>>>(
                hsml, 256, wt + OFFW2(l), wt + OFFW2(l), wt + OFFW2(l),
                b2 + l * H_, b2 + l * H_, b2 + l * H_,
                ybuf, 128, l2s + l * H_, l2b + l * H_, nullptr, nullptr, outp, outp, outp, H_);
        }
    }
}